// Round 1
// baseline (2680.009 us; speedup 1.0000x reference)
//
#include <hip/hip_runtime.h>
#include <hip/hip_bf16.h>

// Problem: y = x(8192x4096) @ W(4096x3072) + b; pad cols to 4096;
// out = (H q H^T-ish) rotor quantizer: fwht(clip(round(fwht(y)/64/0.25),-8,7)*0.25)/64,
// truncated back to 3072 cols. Output fp32, 8192x3072.

#define BM 128
#define BN 128
#define BK 8
#define TM 8
#define TN 8

__global__ __launch_bounds__(256) void gemm_bias_kernel(
    const float* __restrict__ X,   // 8192 x 4096
    const float* __restrict__ W,   // 4096 x 3072
    const float* __restrict__ bias,// 3072
    float* __restrict__ Y)         // 8192 x 3072 (d_out, overwritten later in-place)
{
    __shared__ float As[BK][BM];
    __shared__ float Bs[BK][BN];

    const int tid  = threadIdx.x;
    const int row0 = blockIdx.y * BM;
    const int col0 = blockIdx.x * BN;

    // A tile load: 128x8 floats = 1024 -> 256 threads x float4
    const int a_row  = tid >> 1;         // 0..127
    const int a_col4 = (tid & 1) * 4;    // 0 or 4
    // B tile load: 8x128 floats = 1024 -> 256 threads x float4
    const int b_row  = tid >> 5;         // 0..7
    const int b_col4 = (tid & 31) * 4;   // 0..124

    const int tx = tid & 15;             // 0..15 -> col group
    const int ty = tid >> 4;             // 0..15 -> row group

    const float* Xp = X + (size_t)(row0 + a_row) * 4096 + a_col4;
    const float* Wp = W + (size_t)b_row * 3072 + (col0 + b_col4);

    float acc[TM][TN];
    #pragma unroll
    for (int i = 0; i < TM; ++i)
        #pragma unroll
        for (int j = 0; j < TN; ++j) acc[i][j] = 0.0f;

    for (int k0 = 0; k0 < 4096; k0 += BK) {
        float4 av = *(const float4*)(Xp + k0);
        float4 bv = *(const float4*)(Wp + (size_t)k0 * 3072);

        As[a_col4 + 0][a_row] = av.x;
        As[a_col4 + 1][a_row] = av.y;
        As[a_col4 + 2][a_row] = av.z;
        As[a_col4 + 3][a_row] = av.w;
        *(float4*)&Bs[b_row][b_col4] = bv;
        __syncthreads();

        #pragma unroll
        for (int k = 0; k < BK; ++k) {
            float4 a0 = *(const float4*)&As[k][ty * TM];
            float4 a1 = *(const float4*)&As[k][ty * TM + 4];
            float4 b0 = *(const float4*)&Bs[k][tx * TN];
            float4 b1 = *(const float4*)&Bs[k][tx * TN + 4];
            float ar[TM] = {a0.x, a0.y, a0.z, a0.w, a1.x, a1.y, a1.z, a1.w};
            float br[TN] = {b0.x, b0.y, b0.z, b0.w, b1.x, b1.y, b1.z, b1.w};
            #pragma unroll
            for (int i = 0; i < TM; ++i)
                #pragma unroll
                for (int j = 0; j < TN; ++j)
                    acc[i][j] = fmaf(ar[i], br[j], acc[i][j]);
        }
        __syncthreads();
    }

    // Epilogue: add bias, store (N=3072 exactly divisible, no guards needed)
    #pragma unroll
    for (int i = 0; i < TM; ++i) {
        const int gr = row0 + ty * TM + i;
        float* yp = Y + (size_t)gr * 3072 + col0 + tx * TN;
        #pragma unroll
        for (int j = 0; j < TN; j += 4) {
            float4 v;
            v.x = acc[i][j + 0] + bias[col0 + tx * TN + j + 0];
            v.y = acc[i][j + 1] + bias[col0 + tx * TN + j + 1];
            v.z = acc[i][j + 2] + bias[col0 + tx * TN + j + 2];
            v.w = acc[i][j + 3] + bias[col0 + tx * TN + j + 3];
            *(float4*)(yp + j) = v;
        }
    }
}

// One block per row: load 3072 (pad 1024 zeros), FWHT-4096, scale+quantize,
// FWHT-4096, scale, write back first 3072. In-place on d_out.
__global__ __launch_bounds__(512) void fwht_quant_kernel(float* __restrict__ Y)
{
    __shared__ float s[4096];
    const int row = blockIdx.x;
    float* yrow = Y + (size_t)row * 3072;

    for (int i = threadIdx.x; i < 3072; i += 512) s[i] = yrow[i];
    for (int i = 3072 + threadIdx.x; i < 4096; i += 512) s[i] = 0.0f;
    __syncthreads();

    // forward FWHT (Sylvester ordering; h = 1,2,...,2048)
    for (int h = 1; h < 4096; h <<= 1) {
        #pragma unroll 4
        for (int t = threadIdx.x; t < 2048; t += 512) {
            const int i = ((t & ~(h - 1)) << 1) | (t & (h - 1));
            const int j = i + h;
            const float a = s[i];
            const float b = s[j];
            s[i] = a + b;
            s[j] = a - b;
        }
        __syncthreads();
    }

    // scale by 1/64, quantize: idx = clip(round(v/0.25), -8, 7); q = idx*0.25
    for (int i = threadIdx.x; i < 4096; i += 512) {
        const float v = s[i] * 0.015625f;        // * 1/sqrt(4096)
        float idx = rintf(v * 4.0f);             // round-half-even, matches jnp.round
        idx = fminf(fmaxf(idx, -8.0f), 7.0f);
        s[i] = idx * 0.25f;
    }
    __syncthreads();

    // inverse (same) FWHT
    for (int h = 1; h < 4096; h <<= 1) {
        #pragma unroll 4
        for (int t = threadIdx.x; t < 2048; t += 512) {
            const int i = ((t & ~(h - 1)) << 1) | (t & (h - 1));
            const int j = i + h;
            const float a = s[i];
            const float b = s[j];
            s[i] = a + b;
            s[j] = a - b;
        }
        __syncthreads();
    }

    for (int i = threadIdx.x; i < 3072; i += 512) yrow[i] = s[i] * 0.015625f;
}

extern "C" void kernel_launch(void* const* d_in, const int* in_sizes, int n_in,
                              void* d_out, int out_size, void* d_ws, size_t ws_size,
                              hipStream_t stream) {
    const float* X    = (const float*)d_in[0];   // (4,2048,4096) -> 8192 x 4096
    const float* W    = (const float*)d_in[1];   // 4096 x 3072
    const float* bias = (const float*)d_in[2];   // 3072
    float* out = (float*)d_out;                  // 8192 x 3072

    dim3 ggrid(3072 / BN, 8192 / BM);            // (24, 64)
    gemm_bias_kernel<<<ggrid, 256, 0, stream>>>(X, W, bias, out);

    fwht_quant_kernel<<<8192, 512, 0, stream>>>(out);
}

// Round 2
// 963.165 us; speedup vs baseline: 2.7825x; 2.7825x over previous
//
#include <hip/hip_runtime.h>
#include <hip/hip_bf16.h>
#include <stdint.h>

// y = X(8192x4096) @ W(4096x3072) + b, then rotor quantizer:
// out = fwht(clip(round(fwht(pad(y))/64/0.25),-8,7)*0.25)/64, first 3072 cols.
//
// GEMM via split-bf16 MFMA: A=Ah+Al, B=Bh+Bl (bf16 + bf16 residual),
// C = Ah*Bh + Ah*Bl + Al*Bh  (fp32 MFMA accumulation; Al*Bl ~1e-8, dropped).

#define GM 8192
#define GN 3072
#define GK 4096

typedef __attribute__((ext_vector_type(8))) short short8;  // 8 bf16 = 4 VGPRs
typedef __attribute__((ext_vector_type(4))) float f32x4;

__device__ __forceinline__ void gl2lds16(const void* g, void* l) {
    __builtin_amdgcn_global_load_lds(
        (const __attribute__((address_space(1))) void*)g,
        (__attribute__((address_space(3))) void*)l, 16, 0, 0);
}

// ---------------- split / transpose pre-passes ----------------

__global__ __launch_bounds__(256) void split_x_kernel(
    const float* __restrict__ X,
    __hip_bfloat16* __restrict__ Xh, __hip_bfloat16* __restrict__ Xl)
{
    const size_t i = ((size_t)blockIdx.x * 256 + threadIdx.x) * 4;
    const float4 v = *(const float4*)(X + i);
    float vv[4] = {v.x, v.y, v.z, v.w};
    struct alignas(8) B4 { __hip_bfloat16 v[4]; };
    B4 hb, lb;
    #pragma unroll
    for (int t = 0; t < 4; ++t) {
        __hip_bfloat16 h = __float2bfloat16(vv[t]);
        hb.v[t] = h;
        lb.v[t] = __float2bfloat16(vv[t] - __bfloat162float(h));
    }
    *(B4*)(Xh + i) = hb;
    *(B4*)(Xl + i) = lb;
}

// W: (4096 k) x (3072 n) row-major -> WhT/WlT: (3072 n) x (4096 k) bf16
__global__ __launch_bounds__(256) void split_wt_kernel(
    const float* __restrict__ W,
    __hip_bfloat16* __restrict__ WhT, __hip_bfloat16* __restrict__ WlT)
{
    __shared__ float tile[32][33];
    const int nt = blockIdx.x * 32;
    const int kt = blockIdx.y * 32;
    const int tx = threadIdx.x & 31;
    const int ty = threadIdx.x >> 5;   // 0..7
    #pragma unroll
    for (int r = 0; r < 4; ++r)
        tile[ty + 8 * r][tx] = W[(size_t)(kt + ty + 8 * r) * GN + nt + tx];
    __syncthreads();
    #pragma unroll
    for (int r = 0; r < 4; ++r) {
        const float v = tile[tx][ty + 8 * r];
        __hip_bfloat16 h = __float2bfloat16(v);
        __hip_bfloat16 l = __float2bfloat16(v - __bfloat162float(h));
        const size_t o = (size_t)(nt + ty + 8 * r) * GK + kt + tx;
        WhT[o] = h;
        WlT[o] = l;
    }
}

// ---------------- split-bf16 MFMA GEMM ----------------
// 128x128 tile, BK=32, 4 waves (2x2), each wave 4x4 accs of 16x16x32.
// LDS tiles stored as 128 rows x 32 bf16 (64 B rows), with the four 16-B
// slots of each row XOR-swizzled (slot' = slot ^ ((row>>1)&3)) via the
// GLOBAL address side of global_load_lds, so frag ds_read_b128 is 2-way.

__global__ __launch_bounds__(256) void gemm_bf16x3_kernel(
    const __hip_bfloat16* __restrict__ Xh,
    const __hip_bfloat16* __restrict__ Xl,
    const __hip_bfloat16* __restrict__ WhT,
    const __hip_bfloat16* __restrict__ WlT,
    const float* __restrict__ bias,
    float* __restrict__ Y)
{
    __shared__ __align__(16) __hip_bfloat16 sAh[128 * 32];
    __shared__ __align__(16) __hip_bfloat16 sAl[128 * 32];
    __shared__ __align__(16) __hip_bfloat16 sBh[128 * 32];
    __shared__ __align__(16) __hip_bfloat16 sBl[128 * 32];

    const int tid  = threadIdx.x;
    const int wave = tid >> 6;
    const int lane = tid & 63;
    const int quad = lane >> 4;
    const int l16  = lane & 15;
    const int wm   = (wave & 1) * 64;
    const int wn   = (wave >> 1) * 64;

    const int row0 = blockIdx.y * 128;
    const int col0 = blockIdx.x * 128;

    // staging: 8 x 1KB instrs per tile; this wave does t0, t0+1
    const int t0 = wave * 2;
    const int lr = lane >> 2;                                   // row within 16-group
    const int lc = (((lane & 3) ^ ((lane >> 3) & 3)) * 8);      // swizzled 8-elem slot

    const __hip_bfloat16* gA0h = Xh  + (size_t)(row0 + t0 * 16 + lr) * GK + lc;
    const __hip_bfloat16* gA1h = gA0h + 16 * GK;
    const __hip_bfloat16* gA0l = Xl  + (size_t)(row0 + t0 * 16 + lr) * GK + lc;
    const __hip_bfloat16* gA1l = gA0l + 16 * GK;
    const __hip_bfloat16* gB0h = WhT + (size_t)(col0 + t0 * 16 + lr) * GK + lc;
    const __hip_bfloat16* gB1h = gB0h + 16 * GK;
    const __hip_bfloat16* gB0l = WlT + (size_t)(col0 + t0 * 16 + lr) * GK + lc;
    const __hip_bfloat16* gB1l = gB0l + 16 * GK;

    __hip_bfloat16* dA0 = &sAh[t0 * 512];
    __hip_bfloat16* dA1 = &sAh[(t0 + 1) * 512];
    __hip_bfloat16* dAl0 = &sAl[t0 * 512];
    __hip_bfloat16* dAl1 = &sAl[(t0 + 1) * 512];
    __hip_bfloat16* dB0 = &sBh[t0 * 512];
    __hip_bfloat16* dB1 = &sBh[(t0 + 1) * 512];
    __hip_bfloat16* dBl0 = &sBl[t0 * 512];
    __hip_bfloat16* dBl1 = &sBl[(t0 + 1) * 512];

    // fragment LDS offsets (elements), constant across k-steps
    const int fsw = (quad ^ ((l16 >> 1) & 3)) * 8;
    int offA[4], offB[4];
    #pragma unroll
    for (int i = 0; i < 4; ++i) {
        offA[i] = (wm + i * 16 + l16) * 32 + fsw;
        offB[i] = (wn + i * 16 + l16) * 32 + fsw;
    }

    f32x4 acc[4][4];
    #pragma unroll
    for (int i = 0; i < 4; ++i)
        #pragma unroll
        for (int j = 0; j < 4; ++j)
            acc[i][j] = (f32x4)0.0f;

    for (int k0 = 0; k0 < GK; k0 += 32) {
        gl2lds16(gA0h + k0, dA0);
        gl2lds16(gA1h + k0, dA1);
        gl2lds16(gA0l + k0, dAl0);
        gl2lds16(gA1l + k0, dAl1);
        gl2lds16(gB0h + k0, dB0);
        gl2lds16(gB1h + k0, dB1);
        gl2lds16(gB0l + k0, dBl0);
        gl2lds16(gB1l + k0, dBl1);
        __syncthreads();

        short8 ah[4], al[4], bh[4], bl[4];
        #pragma unroll
        for (int i = 0; i < 4; ++i) {
            ah[i] = *(const short8*)&sAh[offA[i]];
            al[i] = *(const short8*)&sAl[offA[i]];
            bh[i] = *(const short8*)&sBh[offB[i]];
            bl[i] = *(const short8*)&sBl[offB[i]];
        }
        #pragma unroll
        for (int i = 0; i < 4; ++i)
            #pragma unroll
            for (int j = 0; j < 4; ++j) {
                acc[i][j] = __builtin_amdgcn_mfma_f32_16x16x32_bf16(ah[i], bh[j], acc[i][j], 0, 0, 0);
                acc[i][j] = __builtin_amdgcn_mfma_f32_16x16x32_bf16(ah[i], bl[j], acc[i][j], 0, 0, 0);
                acc[i][j] = __builtin_amdgcn_mfma_f32_16x16x32_bf16(al[i], bh[j], acc[i][j], 0, 0, 0);
            }
        __syncthreads();
    }

    // epilogue: C/D layout col=lane&15, row=quad*4+reg
    #pragma unroll
    for (int i = 0; i < 4; ++i) {
        const int r = row0 + wm + i * 16 + quad * 4;
        #pragma unroll
        for (int j = 0; j < 4; ++j) {
            const int c = col0 + wn + j * 16 + l16;
            const float bv = bias[c];
            float* yp = Y + (size_t)r * GN + c;
            #pragma unroll
            for (int g = 0; g < 4; ++g)
                yp[(size_t)g * GN] = acc[i][j][g] + bv;
        }
    }
}

// ---------------- fp32 fallback GEMM (if workspace too small) ----------------

#define BM 128
#define BN 128
#define BK 8
#define TM 8
#define TN 8

__global__ __launch_bounds__(256) void gemm_bias_kernel(
    const float* __restrict__ X, const float* __restrict__ W,
    const float* __restrict__ bias, float* __restrict__ Y)
{
    __shared__ float As[BK][BM];
    __shared__ float Bs[BK][BN];
    const int tid = threadIdx.x;
    const int row0 = blockIdx.y * BM;
    const int col0 = blockIdx.x * BN;
    const int a_row = tid >> 1, a_col4 = (tid & 1) * 4;
    const int b_row = tid >> 5, b_col4 = (tid & 31) * 4;
    const int tx = tid & 15, ty = tid >> 4;
    const float* Xp = X + (size_t)(row0 + a_row) * GK + a_col4;
    const float* Wp = W + (size_t)b_row * GN + (col0 + b_col4);
    float acc[TM][TN];
    #pragma unroll
    for (int i = 0; i < TM; ++i)
        #pragma unroll
        for (int j = 0; j < TN; ++j) acc[i][j] = 0.0f;
    for (int k0 = 0; k0 < GK; k0 += BK) {
        float4 av = *(const float4*)(Xp + k0);
        float4 bv = *(const float4*)(Wp + (size_t)k0 * GN);
        As[a_col4 + 0][a_row] = av.x;
        As[a_col4 + 1][a_row] = av.y;
        As[a_col4 + 2][a_row] = av.z;
        As[a_col4 + 3][a_row] = av.w;
        *(float4*)&Bs[b_row][b_col4] = bv;
        __syncthreads();
        #pragma unroll
        for (int k = 0; k < BK; ++k) {
            float4 a0 = *(const float4*)&As[k][ty * TM];
            float4 a1 = *(const float4*)&As[k][ty * TM + 4];
            float4 b0 = *(const float4*)&Bs[k][tx * TN];
            float4 b1 = *(const float4*)&Bs[k][tx * TN + 4];
            float ar[TM] = {a0.x, a0.y, a0.z, a0.w, a1.x, a1.y, a1.z, a1.w};
            float br[TN] = {b0.x, b0.y, b0.z, b0.w, b1.x, b1.y, b1.z, b1.w};
            #pragma unroll
            for (int i = 0; i < TM; ++i)
                #pragma unroll
                for (int j = 0; j < TN; ++j)
                    acc[i][j] = fmaf(ar[i], br[j], acc[i][j]);
        }
        __syncthreads();
    }
    #pragma unroll
    for (int i = 0; i < TM; ++i) {
        const int gr = row0 + ty * TM + i;
        float* yp = Y + (size_t)gr * GN + col0 + tx * TN;
        #pragma unroll
        for (int j = 0; j < TN; j += 4) {
            float4 v;
            v.x = acc[i][j + 0] + bias[col0 + tx * TN + j + 0];
            v.y = acc[i][j + 1] + bias[col0 + tx * TN + j + 1];
            v.z = acc[i][j + 2] + bias[col0 + tx * TN + j + 2];
            v.w = acc[i][j + 3] + bias[col0 + tx * TN + j + 3];
            *(float4*)(yp + j) = v;
        }
    }
}

// ---------------- FWHT + quantize (per row, in-place on d_out) ----------------

__global__ __launch_bounds__(512) void fwht_quant_kernel(float* __restrict__ Y)
{
    __shared__ float s[4096];
    const int row = blockIdx.x;
    float* yrow = Y + (size_t)row * GN;

    for (int i = threadIdx.x; i < GN; i += 512) s[i] = yrow[i];
    for (int i = GN + threadIdx.x; i < 4096; i += 512) s[i] = 0.0f;
    __syncthreads();

    for (int h = 1; h < 4096; h <<= 1) {
        #pragma unroll 4
        for (int t = threadIdx.x; t < 2048; t += 512) {
            const int i = ((t & ~(h - 1)) << 1) | (t & (h - 1));
            const int j = i + h;
            const float a = s[i];
            const float b = s[j];
            s[i] = a + b;
            s[j] = a - b;
        }
        __syncthreads();
    }

    for (int i = threadIdx.x; i < 4096; i += 512) {
        const float v = s[i] * 0.015625f;
        float idx = rintf(v * 4.0f);
        idx = fminf(fmaxf(idx, -8.0f), 7.0f);
        s[i] = idx * 0.25f;
    }
    __syncthreads();

    for (int h = 1; h < 4096; h <<= 1) {
        #pragma unroll 4
        for (int t = threadIdx.x; t < 2048; t += 512) {
            const int i = ((t & ~(h - 1)) << 1) | (t & (h - 1));
            const int j = i + h;
            const float a = s[i];
            const float b = s[j];
            s[i] = a + b;
            s[j] = a - b;
        }
        __syncthreads();
    }

    for (int i = threadIdx.x; i < GN; i += 512) yrow[i] = s[i] * 0.015625f;
}

// ---------------- launch ----------------

extern "C" void kernel_launch(void* const* d_in, const int* in_sizes, int n_in,
                              void* d_out, int out_size, void* d_ws, size_t ws_size,
                              hipStream_t stream) {
    const float* X    = (const float*)d_in[0];   // 8192 x 4096
    const float* W    = (const float*)d_in[1];   // 4096 x 3072
    const float* bias = (const float*)d_in[2];   // 3072
    float* out = (float*)d_out;                  // 8192 x 3072

    const size_t SZ_XH = (size_t)GM * GK * sizeof(__hip_bfloat16);  // 64 MB
    const size_t SZ_WT = (size_t)GN * GK * sizeof(__hip_bfloat16);  // 24 MB
    const size_t need  = 2 * SZ_XH + 2 * SZ_WT;                     // ~176 MB

    if (ws_size >= need) {
        __hip_bfloat16* Xh  = (__hip_bfloat16*)d_ws;
        __hip_bfloat16* Xl  = (__hip_bfloat16*)((char*)d_ws + SZ_XH);
        __hip_bfloat16* WhT = (__hip_bfloat16*)((char*)d_ws + 2 * SZ_XH);
        __hip_bfloat16* WlT = (__hip_bfloat16*)((char*)d_ws + 2 * SZ_XH + SZ_WT);

        split_x_kernel<<<(GM * (size_t)GK) / (4 * 256), 256, 0, stream>>>(X, Xh, Xl);
        split_wt_kernel<<<dim3(GN / 32, GK / 32), 256, 0, stream>>>(W, WhT, WlT);
        gemm_bf16x3_kernel<<<dim3(GN / 128, GM / 128), 256, 0, stream>>>(Xh, Xl, WhT, WlT, bias, out);
    } else {
        gemm_bias_kernel<<<dim3(GN / BN, GM / BM), 256, 0, stream>>>(X, W, bias, out);
    }

    fwht_quant_kernel<<<GM, 512, 0, stream>>>(out);
}

// Round 3
// 949.791 us; speedup vs baseline: 2.8217x; 1.0141x over previous
//
#include <hip/hip_runtime.h>
#include <hip/hip_bf16.h>
#include <stdint.h>

// y = X(8192x4096) @ W(4096x3072) + b, then rotor quantizer:
// out = fwht(clip(round(fwht(pad(y))/64/0.25),-8,7)*0.25)/64, first 3072 cols.
//
// GEMM via split-bf16 MFMA (32x32x16): A=Ah+Al, B=Bh+Bl,
// C = Ah*Bh + Ah*Bl + Al*Bh (fp32 accum; Al*Bl ~1e-8, dropped).

#define GM 8192
#define GN 3072
#define GK 4096

typedef __attribute__((ext_vector_type(8))) short short8;    // 8 bf16
typedef __attribute__((ext_vector_type(4))) float f32x4;
typedef __attribute__((ext_vector_type(16))) float f32x16;

__device__ __forceinline__ void gl2lds16(const void* g, void* l) {
    __builtin_amdgcn_global_load_lds(
        (const __attribute__((address_space(1))) void*)g,
        (__attribute__((address_space(3))) void*)l, 16, 0, 0);
}

// ---------------- split / transpose pre-passes ----------------

struct alignas(16) B8 { __hip_bfloat16 v[8]; };

__global__ __launch_bounds__(256) void split_x_kernel(
    const float* __restrict__ X,
    __hip_bfloat16* __restrict__ Xh, __hip_bfloat16* __restrict__ Xl)
{
    const size_t i = ((size_t)blockIdx.x * 256 + threadIdx.x) * 8;
    const float4 a = *(const float4*)(X + i);
    const float4 b = *(const float4*)(X + i + 4);
    float vv[8] = {a.x, a.y, a.z, a.w, b.x, b.y, b.z, b.w};
    B8 hb, lb;
    #pragma unroll
    for (int t = 0; t < 8; ++t) {
        __hip_bfloat16 h = __float2bfloat16(vv[t]);
        hb.v[t] = h;
        lb.v[t] = __float2bfloat16(vv[t] - __bfloat162float(h));
    }
    *(B8*)(Xh + i) = hb;
    *(B8*)(Xl + i) = lb;
}

// W: (4096 k) x (3072 n) row-major -> WhT/WlT: (3072 n) x (4096 k) bf16
__global__ __launch_bounds__(256) void split_wt_kernel(
    const float* __restrict__ W,
    __hip_bfloat16* __restrict__ WhT, __hip_bfloat16* __restrict__ WlT)
{
    __shared__ float tile[32][33];
    const int nt = blockIdx.x * 32;
    const int kt = blockIdx.y * 32;
    const int tx = threadIdx.x & 31;
    const int ty = threadIdx.x >> 5;   // 0..7
    #pragma unroll
    for (int r = 0; r < 4; ++r)
        tile[ty + 8 * r][tx] = W[(size_t)(kt + ty + 8 * r) * GN + nt + tx];
    __syncthreads();
    #pragma unroll
    for (int r = 0; r < 4; ++r) {
        const float v = tile[tx][ty + 8 * r];
        __hip_bfloat16 h = __float2bfloat16(v);
        __hip_bfloat16 l = __float2bfloat16(v - __bfloat162float(h));
        const size_t o = (size_t)(nt + ty + 8 * r) * GK + kt + tx;
        WhT[o] = h;
        WlT[o] = l;
    }
}

// ---------------- split-bf16 MFMA GEMM (32x32x16) ----------------
// 128x128 tile, BK=32, 4 waves (2x2), each wave 64x64 as 2x2 of 32x32 accs.
// LDS rows: 32 bf16 (64 B) with 16-B slots XOR-swizzled: slot' = slot ^ ((row>>1)&3).

__global__ __launch_bounds__(256) void gemm_bf16x3_kernel(
    const __hip_bfloat16* __restrict__ Xh,
    const __hip_bfloat16* __restrict__ Xl,
    const __hip_bfloat16* __restrict__ WhT,
    const __hip_bfloat16* __restrict__ WlT,
    const float* __restrict__ bias,
    float* __restrict__ Y)
{
    __shared__ __align__(16) __hip_bfloat16 sAh[128 * 32];
    __shared__ __align__(16) __hip_bfloat16 sAl[128 * 32];
    __shared__ __align__(16) __hip_bfloat16 sBh[128 * 32];
    __shared__ __align__(16) __hip_bfloat16 sBl[128 * 32];

    const int tid  = threadIdx.x;
    const int wave = tid >> 6;
    const int lane = tid & 63;
    const int half = lane >> 5;   // k-half selector (0/1)
    const int l32  = lane & 31;   // m/n within 32-tile
    const int wm   = (wave & 1) * 64;
    const int wn   = (wave >> 1) * 64;

    const int row0 = blockIdx.y * 128;
    const int col0 = blockIdx.x * 128;

    // staging: this wave stages 16-row groups t0, t0+1 of each array
    const int t0 = wave * 2;
    const int lr = lane >> 2;                                   // row within 16-group
    const int lc = (((lane & 3) ^ ((lane >> 3) & 3)) * 8);      // swizzled 8-elem slot

    const __hip_bfloat16* gA0h = Xh  + (size_t)(row0 + t0 * 16 + lr) * GK + lc;
    const __hip_bfloat16* gA1h = gA0h + 16 * GK;
    const __hip_bfloat16* gA0l = Xl  + (size_t)(row0 + t0 * 16 + lr) * GK + lc;
    const __hip_bfloat16* gA1l = gA0l + 16 * GK;
    const __hip_bfloat16* gB0h = WhT + (size_t)(col0 + t0 * 16 + lr) * GK + lc;
    const __hip_bfloat16* gB1h = gB0h + 16 * GK;
    const __hip_bfloat16* gB0l = WlT + (size_t)(col0 + t0 * 16 + lr) * GK + lc;
    const __hip_bfloat16* gB1l = gB0l + 16 * GK;

    __hip_bfloat16* dA0  = &sAh[t0 * 512];
    __hip_bfloat16* dA1  = &sAh[(t0 + 1) * 512];
    __hip_bfloat16* dAl0 = &sAl[t0 * 512];
    __hip_bfloat16* dAl1 = &sAl[(t0 + 1) * 512];
    __hip_bfloat16* dB0  = &sBh[t0 * 512];
    __hip_bfloat16* dB1  = &sBh[(t0 + 1) * 512];
    __hip_bfloat16* dBl0 = &sBl[t0 * 512];
    __hip_bfloat16* dBl1 = &sBl[(t0 + 1) * 512];

    // fragment LDS offsets: [tile][ksub]
    int offA[2][2], offB[2][2];
    #pragma unroll
    for (int i = 0; i < 2; ++i)
        #pragma unroll
        for (int ks = 0; ks < 2; ++ks) {
            const int rA = wm + i * 32 + l32;
            const int rB = wn + i * 32 + l32;
            offA[i][ks] = rA * 32 + ((ks * 2 + half) ^ ((rA >> 1) & 3)) * 8;
            offB[i][ks] = rB * 32 + ((ks * 2 + half) ^ ((rB >> 1) & 3)) * 8;
        }

    f32x16 acc[2][2];
    #pragma unroll
    for (int i = 0; i < 2; ++i)
        #pragma unroll
        for (int j = 0; j < 2; ++j)
            acc[i][j] = (f32x16)0.0f;

    for (int k0 = 0; k0 < GK; k0 += 32) {
        gl2lds16(gA0h + k0, dA0);
        gl2lds16(gA1h + k0, dA1);
        gl2lds16(gA0l + k0, dAl0);
        gl2lds16(gA1l + k0, dAl1);
        gl2lds16(gB0h + k0, dB0);
        gl2lds16(gB1h + k0, dB1);
        gl2lds16(gB0l + k0, dBl0);
        gl2lds16(gB1l + k0, dBl1);
        __syncthreads();

        short8 ah[2][2], al[2][2], bh[2][2], bl[2][2];
        #pragma unroll
        for (int i = 0; i < 2; ++i)
            #pragma unroll
            for (int ks = 0; ks < 2; ++ks) {
                ah[i][ks] = *(const short8*)&sAh[offA[i][ks]];
                al[i][ks] = *(const short8*)&sAl[offA[i][ks]];
                bh[i][ks] = *(const short8*)&sBh[offB[i][ks]];
                bl[i][ks] = *(const short8*)&sBl[offB[i][ks]];
            }
        #pragma unroll
        for (int ks = 0; ks < 2; ++ks)
            #pragma unroll
            for (int i = 0; i < 2; ++i)
                #pragma unroll
                for (int j = 0; j < 2; ++j) {
                    acc[i][j] = __builtin_amdgcn_mfma_f32_32x32x16_bf16(ah[i][ks], bh[j][ks], acc[i][j], 0, 0, 0);
                    acc[i][j] = __builtin_amdgcn_mfma_f32_32x32x16_bf16(ah[i][ks], bl[j][ks], acc[i][j], 0, 0, 0);
                    acc[i][j] = __builtin_amdgcn_mfma_f32_32x32x16_bf16(al[i][ks], bh[j][ks], acc[i][j], 0, 0, 0);
                }
        __syncthreads();
    }

    // epilogue: C/D layout col=lane&31, row=(reg&3)+8*(reg>>2)+4*(lane>>5)
    #pragma unroll
    for (int i = 0; i < 2; ++i)
        #pragma unroll
        for (int j = 0; j < 2; ++j) {
            const int c = col0 + wn + j * 32 + l32;
            const float bv = bias[c];
            #pragma unroll
            for (int r = 0; r < 16; ++r) {
                const int rw = row0 + wm + i * 32 + (r & 3) + 8 * (r >> 2) + 4 * half;
                Y[(size_t)rw * GN + c] = acc[i][j][r] + bv;
            }
        }
}

// ---------------- fp32 fallback GEMM (if workspace too small) ----------------

#define BM 128
#define BN 128
#define BK 8
#define TM 8
#define TN 8

__global__ __launch_bounds__(256) void gemm_bias_kernel(
    const float* __restrict__ X, const float* __restrict__ W,
    const float* __restrict__ bias, float* __restrict__ Y)
{
    __shared__ float As[BK][BM];
    __shared__ float Bs[BK][BN];
    const int tid = threadIdx.x;
    const int row0 = blockIdx.y * BM;
    const int col0 = blockIdx.x * BN;
    const int a_row = tid >> 1, a_col4 = (tid & 1) * 4;
    const int b_row = tid >> 5, b_col4 = (tid & 31) * 4;
    const int tx = tid & 15, ty = tid >> 4;
    const float* Xp = X + (size_t)(row0 + a_row) * GK + a_col4;
    const float* Wp = W + (size_t)b_row * GN + (col0 + b_col4);
    float acc[TM][TN];
    #pragma unroll
    for (int i = 0; i < TM; ++i)
        #pragma unroll
        for (int j = 0; j < TN; ++j) acc[i][j] = 0.0f;
    for (int k0 = 0; k0 < GK; k0 += BK) {
        float4 av = *(const float4*)(Xp + k0);
        float4 bv = *(const float4*)(Wp + (size_t)k0 * GN);
        As[a_col4 + 0][a_row] = av.x;
        As[a_col4 + 1][a_row] = av.y;
        As[a_col4 + 2][a_row] = av.z;
        As[a_col4 + 3][a_row] = av.w;
        *(float4*)&Bs[b_row][b_col4] = bv;
        __syncthreads();
        #pragma unroll
        for (int k = 0; k < BK; ++k) {
            float4 a0 = *(const float4*)&As[k][ty * TM];
            float4 a1 = *(const float4*)&As[k][ty * TM + 4];
            float4 b0 = *(const float4*)&Bs[k][tx * TN];
            float4 b1 = *(const float4*)&Bs[k][tx * TN + 4];
            float ar[TM] = {a0.x, a0.y, a0.z, a0.w, a1.x, a1.y, a1.z, a1.w};
            float br[TN] = {b0.x, b0.y, b0.z, b0.w, b1.x, b1.y, b1.z, b1.w};
            #pragma unroll
            for (int i = 0; i < TM; ++i)
                #pragma unroll
                for (int j = 0; j < TN; ++j)
                    acc[i][j] = fmaf(ar[i], br[j], acc[i][j]);
        }
        __syncthreads();
    }
    #pragma unroll
    for (int i = 0; i < TM; ++i) {
        const int gr = row0 + ty * TM + i;
        float* yp = Y + (size_t)gr * GN + col0 + tx * TN;
        #pragma unroll
        for (int j = 0; j < TN; j += 4) {
            float4 v;
            v.x = acc[i][j + 0] + bias[col0 + tx * TN + j + 0];
            v.y = acc[i][j + 1] + bias[col0 + tx * TN + j + 1];
            v.z = acc[i][j + 2] + bias[col0 + tx * TN + j + 2];
            v.w = acc[i][j + 3] + bias[col0 + tx * TN + j + 3];
            *(float4*)(yp + j) = v;
        }
    }
}

// ---------------- FWHT + quantize (register/shuffle version) ----------------
// 512 threads/row. Thread owns 8 consecutive elems (bits 0-2 in-reg),
// bits 3-8 via shfl_xor, bits 9-11 in-reg after an XOR-swizzled LDS transpose
// to stride-512 ownership. Stage operators commute -> any order valid.
// 2 barriers total (vs 24 in the scalar-LDS version).

__device__ __forceinline__ int swz(int e) {
    int c = e >> 2;
    c ^= (c >> 3) & 7;
    return (c << 2) | (e & 3);
}

__device__ __forceinline__ void bfly3(float v[8]) {
    #pragma unroll
    for (int h = 1; h < 8; h <<= 1)
        #pragma unroll
        for (int g = 0; g < 8; g += 2 * h)
            #pragma unroll
            for (int j = 0; j < h; ++j) {
                const float a = v[g + j], b = v[g + j + h];
                v[g + j] = a + b;
                v[g + j + h] = a - b;
            }
}

__global__ __launch_bounds__(512) void fwht_quant_kernel(float* __restrict__ Y)
{
    __shared__ float s[4096];
    const int tid  = threadIdx.x;
    const int lane = tid & 63;
    float* yrow = Y + (size_t)blockIdx.x * GN;

    float v[8];
    if (tid < 384) {
        const float4 a = *(const float4*)(yrow + tid * 8);
        const float4 b = *(const float4*)(yrow + tid * 8 + 4);
        v[0] = a.x; v[1] = a.y; v[2] = a.z; v[3] = a.w;
        v[4] = b.x; v[5] = b.y; v[6] = b.z; v[7] = b.w;
    } else {
        #pragma unroll
        for (int j = 0; j < 8; ++j) v[j] = 0.0f;
    }

    bfly3(v);  // bits 0-2
    #pragma unroll
    for (int m = 1; m <= 32; m <<= 1)   // bits 3-8
        #pragma unroll
        for (int j = 0; j < 8; ++j) {
            const float o = __shfl_xor(v[j], m, 64);
            v[j] = (lane & m) ? (o - v[j]) : (v[j] + o);
        }

    {   // transpose to stride-512 ownership (XOR-swizzled chunks)
        const int c0 = tid * 2, c1 = tid * 2 + 1;
        *(float4*)&s[(c0 ^ ((c0 >> 3) & 7)) << 2] = make_float4(v[0], v[1], v[2], v[3]);
        *(float4*)&s[(c1 ^ ((c1 >> 3) & 7)) << 2] = make_float4(v[4], v[5], v[6], v[7]);
    }
    __syncthreads();

    float w[8];
    #pragma unroll
    for (int k = 0; k < 8; ++k) w[k] = s[swz(tid + 512 * k)];

    bfly3(w);  // bits 9-11: forward FWHT complete (unnormalized)

    #pragma unroll
    for (int k = 0; k < 8; ++k) {   // idx = clip(round((w/64)/0.25), -8, 7)
        float idx = rintf(w[k] * 0.0625f);
        idx = fminf(fmaxf(idx, -8.0f), 7.0f);
        w[k] = idx * 0.25f;
    }

    bfly3(w);  // inverse, bits 9-11

    #pragma unroll
    for (int k = 0; k < 8; ++k) s[swz(tid + 512 * k)] = w[k];
    __syncthreads();

    {
        const int c0 = tid * 2, c1 = tid * 2 + 1;
        const float4 a = *(const float4*)&s[(c0 ^ ((c0 >> 3) & 7)) << 2];
        const float4 b = *(const float4*)&s[(c1 ^ ((c1 >> 3) & 7)) << 2];
        v[0] = a.x; v[1] = a.y; v[2] = a.z; v[3] = a.w;
        v[4] = b.x; v[5] = b.y; v[6] = b.z; v[7] = b.w;
    }

    #pragma unroll
    for (int m = 1; m <= 32; m <<= 1)   // inverse, bits 3-8
        #pragma unroll
        for (int j = 0; j < 8; ++j) {
            const float o = __shfl_xor(v[j], m, 64);
            v[j] = (lane & m) ? (o - v[j]) : (v[j] + o);
        }
    bfly3(v);  // inverse, bits 0-2

    if (tid < 384) {
        const float sc = 0.015625f;
        float4 a = make_float4(v[0] * sc, v[1] * sc, v[2] * sc, v[3] * sc);
        float4 b = make_float4(v[4] * sc, v[5] * sc, v[6] * sc, v[7] * sc);
        *(float4*)(yrow + tid * 8) = a;
        *(float4*)(yrow + tid * 8 + 4) = b;
    }
}

// ---------------- launch ----------------

extern "C" void kernel_launch(void* const* d_in, const int* in_sizes, int n_in,
                              void* d_out, int out_size, void* d_ws, size_t ws_size,
                              hipStream_t stream) {
    const float* X    = (const float*)d_in[0];   // 8192 x 4096
    const float* W    = (const float*)d_in[1];   // 4096 x 3072
    const float* bias = (const float*)d_in[2];   // 3072
    float* out = (float*)d_out;                  // 8192 x 3072

    const size_t SZ_XH = (size_t)GM * GK * sizeof(__hip_bfloat16);  // 64 MB
    const size_t SZ_WT = (size_t)GN * GK * sizeof(__hip_bfloat16);  // 24 MB
    const size_t need  = 2 * SZ_XH + 2 * SZ_WT;                     // ~176 MB

    if (ws_size >= need) {
        __hip_bfloat16* Xh  = (__hip_bfloat16*)d_ws;
        __hip_bfloat16* Xl  = (__hip_bfloat16*)((char*)d_ws + SZ_XH);
        __hip_bfloat16* WhT = (__hip_bfloat16*)((char*)d_ws + 2 * SZ_XH);
        __hip_bfloat16* WlT = (__hip_bfloat16*)((char*)d_ws + 2 * SZ_XH + SZ_WT);

        split_x_kernel<<<(GM * (size_t)GK) / (8 * 256), 256, 0, stream>>>(X, Xh, Xl);
        split_wt_kernel<<<dim3(GN / 32, GK / 32), 256, 0, stream>>>(W, WhT, WlT);
        gemm_bf16x3_kernel<<<dim3(GN / 128, GM / 128), 256, 0, stream>>>(Xh, Xl, WhT, WlT, bias, out);
    } else {
        gemm_bias_kernel<<<dim3(GN / BN, GM / BM), 256, 0, stream>>>(X, W, bias, out);
    }

    fwht_quant_kernel<<<GM, 512, 0, stream>>>(out);
}

// Round 4
// 500.879 us; speedup vs baseline: 5.3506x; 1.8962x over previous
//
#include <hip/hip_runtime.h>
#include <hip/hip_bf16.h>
#include <stdint.h>

// y = X(8192x4096) @ W(4096x3072) + b, then rotor quantizer:
// out = fwht(clip(round(fwht(pad(y))/64/0.25),-8,7)*0.25)/64, first 3072 cols.
//
// GEMM: single fp16 MFMA (32x32x16), fp32 accumulate. fp16 roundoff gives
// y-error std ~4e-4 -> ~5 quant-level flips/row -> absmax ~0.06 < 0.11 thr.

#define GM 8192
#define GN 3072
#define GK 4096

typedef _Float16 f16;
typedef __attribute__((ext_vector_type(8))) _Float16 f16x8;   // 4 VGPRs
typedef __attribute__((ext_vector_type(16))) float f32x16;

__device__ __forceinline__ void gl2lds16(const void* g, void* l) {
    __builtin_amdgcn_global_load_lds(
        (const __attribute__((address_space(1))) void*)g,
        (__attribute__((address_space(3))) void*)l, 16, 0, 0);
}

// ---------------- cast / transpose pre-passes ----------------

struct alignas(16) H8 { f16 v[8]; };

__global__ __launch_bounds__(256) void split_x_kernel(
    const float* __restrict__ X, f16* __restrict__ Xh)
{
    const size_t i = ((size_t)blockIdx.x * 256 + threadIdx.x) * 8;
    const float4 a = *(const float4*)(X + i);
    const float4 b = *(const float4*)(X + i + 4);
    H8 h;
    h.v[0] = (f16)a.x; h.v[1] = (f16)a.y; h.v[2] = (f16)a.z; h.v[3] = (f16)a.w;
    h.v[4] = (f16)b.x; h.v[5] = (f16)b.y; h.v[6] = (f16)b.z; h.v[7] = (f16)b.w;
    *(H8*)(Xh + i) = h;
}

// W: (4096 k) x (3072 n) row-major -> WT: (3072 n) x (4096 k) fp16
__global__ __launch_bounds__(256) void split_wt_kernel(
    const float* __restrict__ W, f16* __restrict__ WT)
{
    __shared__ float tile[32][33];
    const int nt = blockIdx.x * 32;
    const int kt = blockIdx.y * 32;
    const int tx = threadIdx.x & 31;
    const int ty = threadIdx.x >> 5;   // 0..7
    #pragma unroll
    for (int r = 0; r < 4; ++r)
        tile[ty + 8 * r][tx] = W[(size_t)(kt + ty + 8 * r) * GN + nt + tx];
    __syncthreads();
    #pragma unroll
    for (int r = 0; r < 4; ++r)
        WT[(size_t)(nt + ty + 8 * r) * GK + kt + tx] = (f16)tile[tx][ty + 8 * r];
}

// ---------------- fp16 MFMA GEMM (32x32x16), 128x128 tile, BK=64 ----------------
// LDS rows: 64 halfs (128 B) = 8 x 16-B slots, XOR-swizzled: phys = s ^ (row&7).
// 4 waves (2x2), each wave 64x64 as 2x2 of 32x32 accs, 16 MFMA per barrier.

__global__ __launch_bounds__(256) void gemm_f16_kernel(
    const f16* __restrict__ Xh, const f16* __restrict__ WT,
    const float* __restrict__ bias, float* __restrict__ Y)
{
    __shared__ __align__(16) f16 sA[128 * 64];
    __shared__ __align__(16) f16 sB[128 * 64];

    const int tid  = threadIdx.x;
    const int wave = tid >> 6;
    const int lane = tid & 63;
    const int half = lane >> 5;   // k-half selector (0/1)
    const int l32  = lane & 31;
    const int wm   = (wave & 1) * 64;
    const int wn   = (wave >> 1) * 64;

    const int row0 = blockIdx.y * 128;
    const int col0 = blockIdx.x * 128;

    // staging: each gl2lds16 instr writes 8 rows (64 lanes x 16B = 1 KB).
    // lane -> row base+ (lane>>3), phys slot lane&7; logical slot = (l&7)^((l>>3)&7).
    const int lr8 = lane >> 3;                              // 0..7
    const int lc  = ((lane & 7) ^ ((lane >> 3) & 7)) * 8;   // global col (halfs)

    const f16* gA[4];
    const f16* gB[4];
    f16* dA[4];
    f16* dB[4];
    #pragma unroll
    for (int q = 0; q < 4; ++q) {
        const int g = wave * 4 + q;        // 8-row group index 0..15
        gA[q] = Xh + (size_t)(row0 + g * 8 + lr8) * GK + lc;
        gB[q] = WT + (size_t)(col0 + g * 8 + lr8) * GK + lc;
        dA[q] = &sA[g * 512];
        dB[q] = &sB[g * 512];
    }

    // fragment LDS offsets: [tile i][ksub 0..3]
    int offA[2][4], offB[2][4];
    #pragma unroll
    for (int i = 0; i < 2; ++i)
        #pragma unroll
        for (int ks = 0; ks < 4; ++ks) {
            const int rA = wm + i * 32 + l32;
            const int rB = wn + i * 32 + l32;
            offA[i][ks] = rA * 64 + (((ks * 2 + half) ^ (rA & 7)) * 8);
            offB[i][ks] = rB * 64 + (((ks * 2 + half) ^ (rB & 7)) * 8);
        }

    f32x16 acc[2][2];
    #pragma unroll
    for (int i = 0; i < 2; ++i)
        #pragma unroll
        for (int j = 0; j < 2; ++j)
            acc[i][j] = (f32x16)0.0f;

    for (int k0 = 0; k0 < GK; k0 += 64) {
        #pragma unroll
        for (int q = 0; q < 4; ++q) {
            gl2lds16(gA[q] + k0, dA[q]);
            gl2lds16(gB[q] + k0, dB[q]);
        }
        __syncthreads();

        f16x8 af[2][4], bf[2][4];
        #pragma unroll
        for (int i = 0; i < 2; ++i)
            #pragma unroll
            for (int ks = 0; ks < 4; ++ks) {
                af[i][ks] = *(const f16x8*)&sA[offA[i][ks]];
                bf[i][ks] = *(const f16x8*)&sB[offB[i][ks]];
            }
        #pragma unroll
        for (int ks = 0; ks < 4; ++ks)
            #pragma unroll
            for (int i = 0; i < 2; ++i)
                #pragma unroll
                for (int j = 0; j < 2; ++j)
                    acc[i][j] = __builtin_amdgcn_mfma_f32_32x32x16_f16(af[i][ks], bf[j][ks], acc[i][j], 0, 0, 0);
        __syncthreads();
    }

    // epilogue: C/D layout col=lane&31, row=(reg&3)+8*(reg>>2)+4*(lane>>5)
    #pragma unroll
    for (int i = 0; i < 2; ++i)
        #pragma unroll
        for (int j = 0; j < 2; ++j) {
            const int c = col0 + wn + j * 32 + l32;
            const float bv = bias[c];
            #pragma unroll
            for (int r = 0; r < 16; ++r) {
                const int rw = row0 + wm + i * 32 + (r & 3) + 8 * (r >> 2) + 4 * half;
                Y[(size_t)rw * GN + c] = acc[i][j][r] + bv;
            }
        }
}

// ---------------- fp32 fallback GEMM (if workspace too small) ----------------

#define BM 128
#define BN 128
#define BK 8
#define TM 8
#define TN 8

__global__ __launch_bounds__(256) void gemm_bias_kernel(
    const float* __restrict__ X, const float* __restrict__ W,
    const float* __restrict__ bias, float* __restrict__ Y)
{
    __shared__ float As[BK][BM];
    __shared__ float Bs[BK][BN];
    const int tid = threadIdx.x;
    const int row0 = blockIdx.y * BM;
    const int col0 = blockIdx.x * BN;
    const int a_row = tid >> 1, a_col4 = (tid & 1) * 4;
    const int b_row = tid >> 5, b_col4 = (tid & 31) * 4;
    const int tx = tid & 15, ty = tid >> 4;
    const float* Xp = X + (size_t)(row0 + a_row) * GK + a_col4;
    const float* Wp = W + (size_t)b_row * GN + (col0 + b_col4);
    float acc[TM][TN];
    #pragma unroll
    for (int i = 0; i < TM; ++i)
        #pragma unroll
        for (int j = 0; j < TN; ++j) acc[i][j] = 0.0f;
    for (int k0 = 0; k0 < GK; k0 += BK) {
        float4 av = *(const float4*)(Xp + k0);
        float4 bv = *(const float4*)(Wp + (size_t)k0 * GN);
        As[a_col4 + 0][a_row] = av.x;
        As[a_col4 + 1][a_row] = av.y;
        As[a_col4 + 2][a_row] = av.z;
        As[a_col4 + 3][a_row] = av.w;
        *(float4*)&Bs[b_row][b_col4] = bv;
        __syncthreads();
        #pragma unroll
        for (int k = 0; k < BK; ++k) {
            float4 a0 = *(const float4*)&As[k][ty * TM];
            float4 a1 = *(const float4*)&As[k][ty * TM + 4];
            float4 b0 = *(const float4*)&Bs[k][tx * TN];
            float4 b1 = *(const float4*)&Bs[k][tx * TN + 4];
            float ar[TM] = {a0.x, a0.y, a0.z, a0.w, a1.x, a1.y, a1.z, a1.w};
            float br[TN] = {b0.x, b0.y, b0.z, b0.w, b1.x, b1.y, b1.z, b1.w};
            #pragma unroll
            for (int i = 0; i < TM; ++i)
                #pragma unroll
                for (int j = 0; j < TN; ++j)
                    acc[i][j] = fmaf(ar[i], br[j], acc[i][j]);
        }
        __syncthreads();
    }
    #pragma unroll
    for (int i = 0; i < TM; ++i) {
        const int gr = row0 + ty * TM + i;
        float* yp = Y + (size_t)gr * GN + col0 + tx * TN;
        #pragma unroll
        for (int j = 0; j < TN; j += 4) {
            float4 v;
            v.x = acc[i][j + 0] + bias[col0 + tx * TN + j + 0];
            v.y = acc[i][j + 1] + bias[col0 + tx * TN + j + 1];
            v.z = acc[i][j + 2] + bias[col0 + tx * TN + j + 2];
            v.w = acc[i][j + 3] + bias[col0 + tx * TN + j + 3];
            *(float4*)(yp + j) = v;
        }
    }
}

// ---------------- FWHT + quantize: 256 thr x 16 elems, register butterflies ----
// 4096 = 16*16*16: three 4-bit register phases; ownership moved by padded-LDS
// transposes (pad p(e)=e+(e>>4) -> all access patterns conflict-free).
// No shuffles; 4 barriers total.

__device__ __forceinline__ int pmap(int e) { return e + (e >> 4); }

__device__ __forceinline__ void bfly16(float v[16]) {
    #pragma unroll
    for (int h = 1; h < 16; h <<= 1)
        #pragma unroll
        for (int g = 0; g < 16; g += 2 * h)
            #pragma unroll
            for (int j = 0; j < h; ++j) {
                const float a = v[g + j], b = v[g + j + h];
                v[g + j] = a + b;
                v[g + j + h] = a - b;
            }
}

__global__ __launch_bounds__(256) void fwht_quant_kernel(float* __restrict__ Y)
{
    __shared__ float s[4096 + 256];
    const int t = threadIdx.x;
    float* yrow = Y + (size_t)blockIdx.x * GN;

    // L1 ownership: e = 16*t + j (bits 0-3 in reg)
    float v[16];
    if (t < 192) {
        #pragma unroll
        for (int q = 0; q < 4; ++q) {
            const float4 a = *(const float4*)(yrow + t * 16 + q * 4);
            v[q * 4 + 0] = a.x; v[q * 4 + 1] = a.y;
            v[q * 4 + 2] = a.z; v[q * 4 + 3] = a.w;
        }
    } else {
        #pragma unroll
        for (int j = 0; j < 16; ++j) v[j] = 0.0f;
    }

    bfly16(v);                                   // bits 0-3

    #pragma unroll
    for (int j = 0; j < 16; ++j) s[pmap(t * 16 + j)] = v[j];
    __syncthreads();
    // L2 ownership: e = (t&15) + 16*j + 256*(t>>4) (bits 4-7 in reg)
    #pragma unroll
    for (int j = 0; j < 16; ++j) v[j] = s[pmap((t & 15) + 16 * j + 256 * (t >> 4))];

    bfly16(v);                                   // bits 4-7

    // write back to own L2 cells (no barrier needed: same cells we just read)
    #pragma unroll
    for (int j = 0; j < 16; ++j) s[pmap((t & 15) + 16 * j + 256 * (t >> 4))] = v[j];
    __syncthreads();
    // L3 ownership: e = t + 256*j (bits 8-11 in reg)
    #pragma unroll
    for (int j = 0; j < 16; ++j) v[j] = s[pmap(t + 256 * j)];

    bfly16(v);                                   // bits 8-11: forward done (unnormalized)

    #pragma unroll
    for (int j = 0; j < 16; ++j) {               // idx = clip(round((v/64)/0.25), -8, 7)
        float idx = rintf(v[j] * 0.0625f);
        idx = fminf(fmaxf(idx, -8.0f), 7.0f);
        v[j] = idx * 0.25f;
    }

    bfly16(v);                                   // inverse bits 8-11

    #pragma unroll
    for (int j = 0; j < 16; ++j) s[pmap(t + 256 * j)] = v[j];
    __syncthreads();
    #pragma unroll
    for (int j = 0; j < 16; ++j) v[j] = s[pmap((t & 15) + 16 * j + 256 * (t >> 4))];

    bfly16(v);                                   // inverse bits 4-7

    #pragma unroll
    for (int j = 0; j < 16; ++j) s[pmap((t & 15) + 16 * j + 256 * (t >> 4))] = v[j];
    __syncthreads();
    #pragma unroll
    for (int j = 0; j < 16; ++j) v[j] = s[pmap(t * 16 + j)];

    bfly16(v);                                   // inverse bits 0-3

    if (t < 192) {
        const float sc = 0.015625f;
        #pragma unroll
        for (int q = 0; q < 4; ++q) {
            float4 a = make_float4(v[q * 4 + 0] * sc, v[q * 4 + 1] * sc,
                                   v[q * 4 + 2] * sc, v[q * 4 + 3] * sc);
            *(float4*)(yrow + t * 16 + q * 4) = a;
        }
    }
}

// ---------------- launch ----------------

extern "C" void kernel_launch(void* const* d_in, const int* in_sizes, int n_in,
                              void* d_out, int out_size, void* d_ws, size_t ws_size,
                              hipStream_t stream) {
    const float* X    = (const float*)d_in[0];   // 8192 x 4096
    const float* W    = (const float*)d_in[1];   // 4096 x 3072
    const float* bias = (const float*)d_in[2];   // 3072
    float* out = (float*)d_out;                  // 8192 x 3072

    const size_t SZ_XH = (size_t)GM * GK * sizeof(f16);  // 64 MB
    const size_t SZ_WT = (size_t)GN * GK * sizeof(f16);  // 24 MB
    const size_t need  = SZ_XH + SZ_WT;                  // 88 MB

    if (ws_size >= need) {
        f16* Xh = (f16*)d_ws;
        f16* WT = (f16*)((char*)d_ws + SZ_XH);

        split_x_kernel<<<(GM * (size_t)GK) / (8 * 256), 256, 0, stream>>>(X, Xh);
        split_wt_kernel<<<dim3(GN / 32, GK / 32), 256, 0, stream>>>(W, WT);
        gemm_f16_kernel<<<dim3(GN / 128, GM / 128), 256, 0, stream>>>(Xh, WT, bias, out);
    } else {
        gemm_bias_kernel<<<dim3(GN / BN, GM / BM), 256, 0, stream>>>(X, W, bias, out);
    }

    fwht_quant_kernel<<<GM, 256, 0, stream>>>(out);
}